// Round 1
// baseline (76.219 us; speedup 1.0000x reference)
//
#include <hip/hip_runtime.h>

// GHM weight: pred (32,8192,80) f32, target same shape i32{0,1}, acc_sum (10) f32.
// out = per-element weight = (tot / (0.1*acc+0.9*cnt[bin])) / n_nonempty, 0 for empty/overflow.
// tot = shape[-2]*shape[-1] = 8192*80 = 655360 (fixed by problem).

#define BINS 10
#define NBIN 11          // 10 bins + overflow bucket
constexpr int NB1 = 2048;   // hist grid blocks (partials leading dim)
constexpr float TOT = 655360.0f;

__global__ __launch_bounds__(256) void ghm_hist(
    const float4* __restrict__ pred, const int4* __restrict__ tgt,
    int* __restrict__ partials /* [NBIN][NB1] */, int n4)
{
    int c[NBIN];
#pragma unroll
    for (int b = 0; b < NBIN; ++b) c[b] = 0;

    const int tid = threadIdx.x;
    const int gid = blockIdx.x * blockDim.x + tid;
    const int stride = gridDim.x * blockDim.x;

    for (int i = gid; i < n4; i += stride) {
        float4 p = pred[i];
        int4   t = tgt[i];
        float pv[4] = {p.x, p.y, p.z, p.w};
        int   tv[4] = {t.x, t.y, t.z, t.w};
#pragma unroll
        for (int k = 0; k < 4; ++k) {
            float g = fabsf(pv[k] - (float)tv[k]);
            int raw = (int)floorf(g * 10.0f);
            int idx = (g < 1.000001f) ? (raw < BINS - 1 ? raw : BINS - 1) : BINS;
#pragma unroll
            for (int b = 0; b < NBIN; ++b) c[b] += (idx == b) ? 1 : 0;
        }
    }

    // wave (64-lane) reduction per bin, then cross-wave via LDS
    __shared__ int lds[4][NBIN];
    const int lane = tid & 63;
    const int wv = tid >> 6;
#pragma unroll
    for (int b = 0; b < NBIN; ++b) {
        int v = c[b];
#pragma unroll
        for (int off = 32; off > 0; off >>= 1) v += __shfl_down(v, off, 64);
        if (lane == 0) lds[wv][b] = v;
    }
    __syncthreads();
    if (tid < NBIN) {
        int s = lds[0][tid] + lds[1][tid] + lds[2][tid] + lds[3][tid];
        partials[tid * NB1 + blockIdx.x] = s;   // non-atomic: fully written each call
    }
}

// 11 waves: wave w reduces bin w's partials; thread 0 computes final per-bin weights.
__global__ __launch_bounds__(704) void ghm_weights(
    const int* __restrict__ partials, const float* __restrict__ acc_sum,
    float* __restrict__ w_final /* [NBIN] */)
{
    const int tid = threadIdx.x;
    const int wv = tid >> 6;      // bin 0..10
    const int lane = tid & 63;

    int s = 0;
    for (int i = lane; i < NB1; i += 64) s += partials[wv * NB1 + i];
#pragma unroll
    for (int off = 32; off > 0; off >>= 1) s += __shfl_down(s, off, 64);

    __shared__ int cnt[NBIN];
    if (lane == 0) cnt[wv] = s;
    __syncthreads();

    if (tid == 0) {
        float n = 0.0f;
        for (int b = 0; b < BINS; ++b) n += (cnt[b] > 0) ? 1.0f : 0.0f;
        float nmax = n > 1.0f ? n : 1.0f;
        for (int b = 0; b < BINS; ++b) {
            float w = 0.0f;
            if (cnt[b] > 0) {
                float na = 0.1f * acc_sum[b] + 0.9f * (float)cnt[b]; // EMA (ref op order)
                float bw = TOT / na;
                w = bw / nmax;
            }
            w_final[b] = w;
        }
        w_final[BINS] = 0.0f;   // overflow bucket
    }
}

__global__ __launch_bounds__(256) void ghm_apply(
    const float4* __restrict__ pred, const int4* __restrict__ tgt,
    const float* __restrict__ w_final, float4* __restrict__ out, int n4)
{
    __shared__ float w[NBIN];   // 11 addrs -> 11 distinct banks -> conflict-free broadcast
    if (threadIdx.x < NBIN) w[threadIdx.x] = w_final[threadIdx.x];
    __syncthreads();

    const int gid = blockIdx.x * blockDim.x + threadIdx.x;
    const int stride = gridDim.x * blockDim.x;

    for (int i = gid; i < n4; i += stride) {
        float4 p = pred[i];
        int4   t = tgt[i];
        float pv[4] = {p.x, p.y, p.z, p.w};
        int   tv[4] = {t.x, t.y, t.z, t.w};
        float ov[4];
#pragma unroll
        for (int k = 0; k < 4; ++k) {
            float g = fabsf(pv[k] - (float)tv[k]);
            int raw = (int)floorf(g * 10.0f);
            int idx = (g < 1.000001f) ? (raw < BINS - 1 ? raw : BINS - 1) : BINS;
            ov[k] = w[idx];
        }
        out[i] = make_float4(ov[0], ov[1], ov[2], ov[3]);
    }
}

extern "C" void kernel_launch(void* const* d_in, const int* in_sizes, int n_in,
                              void* d_out, int out_size, void* d_ws, size_t ws_size,
                              hipStream_t stream) {
    const float* pred    = (const float*)d_in[0];
    const int*   tgt     = (const int*)d_in[1];
    const float* acc_sum = (const float*)d_in[2];
    float*       out     = (float*)d_out;

    const int N  = in_sizes[0];        // 20,971,520 (divisible by 4)
    const int n4 = N / 4;

    int*   partials = (int*)d_ws;                              // NBIN*NB1 ints = 90 KiB
    float* w_final  = (float*)((char*)d_ws + NBIN * NB1 * sizeof(int));

    ghm_hist<<<NB1, 256, 0, stream>>>(
        (const float4*)pred, (const int4*)tgt, partials, n4);
    ghm_weights<<<1, 704, 0, stream>>>(partials, acc_sum, w_final);
    ghm_apply<<<2048, 256, 0, stream>>>(
        (const float4*)pred, (const int4*)tgt, w_final, (float4*)out, n4);
}

// Round 2
// 75.464 us; speedup vs baseline: 1.0100x; 1.0100x over previous
//
#include <hip/hip_runtime.h>
#include <stdint.h>

// GHM weight: pred (32,8192,80) f32 in [0,1), target i32 {0,1}, acc_sum (10) f32.
// g = |pred - t| is in [0,1] => overflow bucket (idx==10) unreachable;
// idx = min((int)(g*10), 9) matches the reference exactly on this domain
// (g==1.0: ref floor(10.0)=10, valid, min(10,9)=9 == ours).

#define BINS 10
constexpr int NB1 = 2048;        // hist grid blocks
constexpr float TOT = 655360.0f; // shape[-2]*shape[-1] = 8192*80

__global__ __launch_bounds__(256) void ghm_hist(
    const float4* __restrict__ pred, const int4* __restrict__ tgt,
    int* __restrict__ partials /* [BINS][NB1] */, int n4)
{
    const int tid = threadIdx.x;
    const int gid = blockIdx.x * blockDim.x + tid;
    const int stride = gridDim.x * blockDim.x;

    // packed histogram: 10 bins x 6-bit fields in one uint64.
    // flushed to c[] before any field can exceed 63 elements.
    uint64_t pc = 0;
    int elems = 0;
    int c[BINS];
#pragma unroll
    for (int b = 0; b < BINS; ++b) c[b] = 0;

    constexpr int B = 5;          // 5 float4+int4 pairs in flight -> 10 outstanding loads
    int i = gid;
    for (; i + (B - 1) * stride < n4; i += B * stride) {
        float4 p[B]; int4 t[B];
#pragma unroll
        for (int k = 0; k < B; ++k) { p[k] = pred[i + k * stride]; t[k] = tgt[i + k * stride]; }
#pragma unroll
        for (int k = 0; k < B; ++k) {
            const float pv[4] = {p[k].x, p[k].y, p[k].z, p[k].w};
            const int   tv[4] = {t[k].x, t[k].y, t[k].z, t[k].w};
#pragma unroll
            for (int e = 0; e < 4; ++e) {
                float g   = fabsf(pv[e] - (float)tv[e]);
                int   raw = (int)(g * 10.0f);            // trunc == floor (g >= 0)
                int   idx = raw < BINS - 1 ? raw : BINS - 1;
                pc += 1ULL << (6 * idx);
            }
        }
        elems += 4 * B;
        if (elems >= 60) {        // worst case: all 60 in one bin == field max 63
#pragma unroll
            for (int b = 0; b < BINS; ++b) c[b] += (int)((pc >> (6 * b)) & 63u);
            pc = 0; elems = 0;
        }
    }
    for (; i < n4; i += stride) { // tail (not taken for the bench shape)
        float4 p = pred[i]; int4 t = tgt[i];
        const float pv[4] = {p.x, p.y, p.z, p.w};
        const int   tv[4] = {t.x, t.y, t.z, t.w};
#pragma unroll
        for (int e = 0; e < 4; ++e) {
            float g   = fabsf(pv[e] - (float)tv[e]);
            int   raw = (int)(g * 10.0f);
            int   idx = raw < BINS - 1 ? raw : BINS - 1;
            pc += 1ULL << (6 * idx);
        }
        elems += 4;
        if (elems >= 60) {
#pragma unroll
            for (int b = 0; b < BINS; ++b) c[b] += (int)((pc >> (6 * b)) & 63u);
            pc = 0; elems = 0;
        }
    }
#pragma unroll
    for (int b = 0; b < BINS; ++b) c[b] += (int)((pc >> (6 * b)) & 63u);

    // wave reduce, then cross-wave via LDS
    __shared__ int lds[4][BINS];
    const int lane = tid & 63;
    const int wv = tid >> 6;
#pragma unroll
    for (int b = 0; b < BINS; ++b) {
        int v = c[b];
#pragma unroll
        for (int off = 32; off > 0; off >>= 1) v += __shfl_down(v, off, 64);
        if (lane == 0) lds[wv][b] = v;
    }
    __syncthreads();
    if (tid < BINS) {
        int s = lds[0][tid] + lds[1][tid] + lds[2][tid] + lds[3][tid];
        partials[tid * NB1 + blockIdx.x] = s;   // non-atomic, fully rewritten each call
    }
}

// 10 waves: wave w reduces bin w's partials; thread 0 computes per-bin weights.
__global__ __launch_bounds__(640) void ghm_weights(
    const int* __restrict__ partials, const float* __restrict__ acc_sum,
    float* __restrict__ w_final /* [BINS] */)
{
    const int tid = threadIdx.x;
    const int wv = tid >> 6;      // bin 0..9
    const int lane = tid & 63;

    int s = 0;
    for (int i = lane; i < NB1; i += 64) s += partials[wv * NB1 + i];
#pragma unroll
    for (int off = 32; off > 0; off >>= 1) s += __shfl_down(s, off, 64);

    __shared__ int cnt[BINS];
    if (lane == 0) cnt[wv] = s;
    __syncthreads();

    if (tid == 0) {
        float n = 0.0f;
        for (int b = 0; b < BINS; ++b) n += (cnt[b] > 0) ? 1.0f : 0.0f;
        float nmax = n > 1.0f ? n : 1.0f;
        for (int b = 0; b < BINS; ++b) {
            float w = 0.0f;
            if (cnt[b] > 0) {
                float na = 0.1f * acc_sum[b] + 0.9f * (float)cnt[b]; // EMA, ref op order
                float bw = TOT / na;
                w = bw / nmax;
            }
            w_final[b] = w;
        }
    }
}

__global__ __launch_bounds__(256) void ghm_apply(
    const float4* __restrict__ pred, const int4* __restrict__ tgt,
    const float* __restrict__ w_final, float4* __restrict__ out, int n4)
{
    __shared__ float w[BINS];   // 10 addrs -> 10 distinct banks -> conflict-free broadcast
    if (threadIdx.x < BINS) w[threadIdx.x] = w_final[threadIdx.x];
    __syncthreads();

    const int gid = blockIdx.x * blockDim.x + threadIdx.x;
    const int stride = gridDim.x * blockDim.x;

    constexpr int B = 4;
    int i = gid;
    for (; i + (B - 1) * stride < n4; i += B * stride) {
        float4 p[B]; int4 t[B];
#pragma unroll
        for (int k = 0; k < B; ++k) { p[k] = pred[i + k * stride]; t[k] = tgt[i + k * stride]; }
#pragma unroll
        for (int k = 0; k < B; ++k) {
            const float pv[4] = {p[k].x, p[k].y, p[k].z, p[k].w};
            const int   tv[4] = {t[k].x, t[k].y, t[k].z, t[k].w};
            float ov[4];
#pragma unroll
            for (int e = 0; e < 4; ++e) {
                float g   = fabsf(pv[e] - (float)tv[e]);
                int   raw = (int)(g * 10.0f);
                int   idx = raw < BINS - 1 ? raw : BINS - 1;
                ov[e] = w[idx];
            }
            out[i + k * stride] = make_float4(ov[0], ov[1], ov[2], ov[3]);
        }
    }
    for (; i < n4; i += stride) {
        float4 p = pred[i]; int4 t = tgt[i];
        const float pv[4] = {p.x, p.y, p.z, p.w};
        const int   tv[4] = {t.x, t.y, t.z, t.w};
        float ov[4];
#pragma unroll
        for (int e = 0; e < 4; ++e) {
            float g   = fabsf(pv[e] - (float)tv[e]);
            int   raw = (int)(g * 10.0f);
            int   idx = raw < BINS - 1 ? raw : BINS - 1;
            ov[e] = w[idx];
        }
        out[i] = make_float4(ov[0], ov[1], ov[2], ov[3]);
    }
}

extern "C" void kernel_launch(void* const* d_in, const int* in_sizes, int n_in,
                              void* d_out, int out_size, void* d_ws, size_t ws_size,
                              hipStream_t stream) {
    const float* pred    = (const float*)d_in[0];
    const int*   tgt     = (const int*)d_in[1];
    const float* acc_sum = (const float*)d_in[2];
    float*       out     = (float*)d_out;

    const int N  = in_sizes[0];   // 20,971,520 (divisible by 4)
    const int n4 = N / 4;

    int*   partials = (int*)d_ws;                                   // BINS*NB1 ints
    float* w_final  = (float*)((char*)d_ws + BINS * NB1 * sizeof(int));

    ghm_hist<<<NB1, 256, 0, stream>>>(
        (const float4*)pred, (const int4*)tgt, partials, n4);
    ghm_weights<<<1, 640, 0, stream>>>(partials, acc_sum, w_final);
    ghm_apply<<<2048, 256, 0, stream>>>(
        (const float4*)pred, (const int4*)tgt, w_final, (float4*)out, n4);
}